// Round 15
// baseline (257.659 us; speedup 1.0000x reference)
//
#include <hip/hip_runtime.h>

// GraphDecoder (NRI) — round 24: edge14 = half-kT double-buffered Hs.
// R23 baseline 192.2us (edge 87.1, MfmaUtil 35 / VALUBusy 38.5, ~27% stall).
// The attackable stall: H-build serializes between barriers. edge14 splits
// each kT into 2 half-phases; Hs[2][16][64][8] (same 32KB) lets phase h MFMA
// on buf[h&1] while building buf[(h+1)&1] IN the same phase (disjoint bufs,
// 1 barrier/phase, same 8 barriers total, build hidden under MFMA). sreg
// shrinks 32->16 VGPR (4 slots/half, reload-in-place); b2 preloaded (8 regs)
// removing exposed epilogue loads. ~92 VGPR + 64 AGPR = 156 <= 170, (256,3).
// prep / outmlp6 byte-identical to R23 (proven). B=32,N=64,F=128,K=4,E=4032.

#define B_ 32
#define N_ 64
#define F_ 128
#define K_ 4
#define E_ 4032

// ws layout (bytes): total 9,961,472 <= proven 9,994,240
#define WS_W2T 0u
#define WS_R   524288u
#define WS_S   4718592u
#define WS_AGG 8912896u

typedef unsigned short u16;
typedef u16    u16x4  __attribute__((ext_vector_type(4)));
typedef u16    u16x8  __attribute__((ext_vector_type(8)));
typedef __bf16 bf16x8 __attribute__((ext_vector_type(8)));
typedef float  f32x4  __attribute__((ext_vector_type(4)));
typedef float  f32x16 __attribute__((ext_vector_type(16)));

__device__ __forceinline__ u16 f2bf(float f) {
    unsigned u; __builtin_memcpy(&u, &f, 4);
    return (u16)((u + 0x7FFFu + ((u >> 16) & 1u)) >> 16);
}
__device__ __forceinline__ float bf2f(u16 u) {
    unsigned v = ((unsigned)u) << 16;
    float f; __builtin_memcpy(&f, &v, 4); return f;
}

// raw barrier (LDS-only handoff; keeps vmem prefetch in flight)
#define LBAR() do { \
    asm volatile("s_waitcnt lgkmcnt(0)" ::: "memory"); \
    __builtin_amdgcn_s_barrier(); \
    __builtin_amdgcn_sched_barrier(0); \
} while (0)

// ---------------- fused prep (W2 -> cf bf16 chunks) + R/S2 tables (R23-proven) ----------------
// S2 kk-chunked: S2[((k*8+kc)*2048 + b*64 + row)*32 + kk_local]  (kc = kk>>5)
__global__ __launch_bounds__(256) void prep_rs_kernel(
    const float* __restrict__ W2, const float* __restrict__ x,
    const float* __restrict__ W1, const float* __restrict__ b1,
    u16* __restrict__ W2t, u16* __restrict__ R, u16* __restrict__ S)
{
    __shared__ u16 ldsA[64 * 136];
    __shared__ u16 ldsW[32 * 136];
    const int tid = threadIdx.x;

    if (blockIdx.x < 1024) {
        // linear read of W2 (coalesced); scattered 2B writes (fire-and-forget).
        unsigned gid = blockIdx.x * 256u + tid;
        unsigned n = gid & 255u, kk = (gid >> 8) & 255u, k = gid >> 16;
        unsigned dst = (k * 8u + (kk >> 5)) * 8192u
                     + ((((kk >> 4) & 1u) * 2u) + ((kk >> 3) & 1u)) * 2048u
                     + n * 8u + (kk & 7u);
        W2t[dst] = f2bf(W2[gid]);
        return;
    }

    // part 2: R/S tables. 1024 blocks: (k, half, b) x ch4; ch covers 2 c-chunks.
    const int lane = tid & 63, w = tid >> 6;
    const int quad = lane >> 4, mloc = lane & 15;
    const int bx = blockIdx.x - 1024;
    const int ch = bx & 3;
    const int bq = bx >> 2;
    const int k = bq >> 6, half = (bq >> 5) & 1, b = bq & 31;

    for (int idx = tid; idx < 2048; idx += 256) {
        int row = idx >> 5, c4 = idx & 31;
        f32x4 v = *(const f32x4*)&x[(b * 64 + row) * 128 + c4 * 4];
        u16x4 o;
#pragma unroll
        for (int e = 0; e < 4; ++e) o[e] = f2bf(v[e]);
        *(u16x4*)&ldsA[row * 136 + c4 * 4] = o;
    }
    __syncthreads();

    bf16x8 aF[4];
#pragma unroll
    for (int ks = 0; ks < 4; ++ks)
        aF[ks] = *(const bf16x8*)&ldsA[(w * 16 + mloc) * 136 + quad * 8 + ks * 32];

    u16* dst = half ? S : R;
    for (int c = ch * 2; c < ch * 2 + 2; ++c) {
        __syncthreads();
        for (int idx = tid; idx < 4096; idx += 256) {
            int n = idx & 31, f = idx >> 5;
            ldsW[n * 136 + f] = f2bf(W1[(k * 256 + half * 128 + f) * 256 + c * 32 + n]);
        }
        __syncthreads();
#pragma unroll
        for (int nt = 0; nt < 2; ++nt) {
            f32x4 acc = (f32x4){0.f, 0.f, 0.f, 0.f};
            const int boff = (nt * 16 + mloc) * 136 + quad * 8;
#pragma unroll
            for (int ks = 0; ks < 4; ++ks)
                acc = __builtin_amdgcn_mfma_f32_16x16x32_bf16(
                    aF[ks], *(const bf16x8*)&ldsW[boff + ks * 32], acc, 0, 0, 0);
            const int n = c * 32 + nt * 16 + mloc;
            const float bias = half ? 0.f : b1[k * 256 + n];
#pragma unroll
            for (int r = 0; r < 4; ++r) {
                int row = w * 16 + quad * 4 + r;
                if (half) {
                    dst[((size_t)((k * 8 + c) * 2048 + b * 64 + row)) * 32 + nt * 16 + mloc]
                        = f2bf(acc[r] + bias);
                } else {
                    dst[((size_t)(k * 2048 + b * 64 + row)) * 256 + n] = f2bf(acc[r] + bias);
                }
            }
        }
    }
}

// ---------------- edge kernel: half-kT dbuf Hs, build hidden under MFMA ----------------
__global__ __launch_bounds__(256, 3) void edge14_kernel(
    const u16* __restrict__ R, const u16* __restrict__ S2,
    const float* __restrict__ rel, const u16* __restrict__ W2t,
    const float* __restrict__ b2, u16* __restrict__ aggb)
{
    __shared__ u16   Hs[2][16][64][8];  // 2 x 16KB half-kT buffers (32KB total)
    __shared__ float Rf[4][256];        // receiver R rows, f32 — written once
    __shared__ float rtS[4][64];        // rel_type [k][j], self=0 — written once

    const int tid  = threadIdx.x;
    const int lane = tid & 63;
    const int w    = tid >> 6;          // n-quarter (MFMA) AND kk32-subgroup (build)
    const int l31  = lane & 31;
    const int lh   = lane >> 5;
    const int bid  = ((blockIdx.x & 7) << 8) | (blockIdx.x >> 3);
    const int b    = bid >> 6;
    const int i    = bid & 63;          // receiver node

    {
        const int k = tid >> 6, j = tid & 63;
        float v = 0.f;
        if (j != i) v = rel[((size_t)(b * E_) + i * 63 + (j - (j > i))) * 4 + k];
        rtS[k][j] = v;
    }
    {
        const int k = tid >> 6, e4 = tid & 63;
        u16x4 t4 = *(const u16x4*)&R[((size_t)(k * 2048 + b * 64 + i)) * 256 + e4 * 4];
#pragma unroll
        for (int e = 0; e < 4; ++e) Rf[k][e4 * 4 + e] = bf2f(t4[e]);
    }

    // sreg: 4 slots for the NEXT half-kT to build (reloaded in place each phase)
    u16x8 sreg[4];
#pragma unroll
    for (int s = 0; s < 4; ++s)
        sreg[s] = *(const u16x8*)&S2[((size_t)(s * 2048 + b * 64 + lane)) * 32 + w * 8];

    // preload biases (removes exposed L2 loads from epilogues)
    float b2r[4][2];
#pragma unroll
    for (int kT = 0; kT < 4; ++kT)
#pragma unroll
        for (int nt = 0; nt < 2; ++nt)
            b2r[kT][nt] = b2[kT * 256 + w * 64 + nt * 32 + l31];

    __syncthreads();

    // build half 0 into Hs[0] (planes s*4+w hold kk_in_half = s*32 + w*8 + e)
#pragma unroll
    for (int s = 0; s < 4; ++s) {
        const float* rp = &Rf[0][s * 32 + w * 8];
        f32x4 r0 = *(const f32x4*)rp, r1 = *(const f32x4*)(rp + 4);
        bf16x8 o;
#pragma unroll
        for (int e = 0; e < 4; ++e) {
            o[e]     = (__bf16)fmaxf(r0[e] + bf2f(sreg[s][e]),     0.f);
            o[4 + e] = (__bf16)fmaxf(r1[e] + bf2f(sreg[s][4 + e]), 0.f);
        }
        *(bf16x8*)&Hs[0][s * 4 + w][lane][0] = o;
    }

    const u16* Wb = W2t + lh * 2048 + (w * 64 + l31) * 8;
    bf16x8 Bb[2][2][2];   // [chunk parity][ks2][nt] — static indices
#pragma unroll
    for (int ks2 = 0; ks2 < 2; ++ks2) {
        const u16* wp = Wb + ks2 * 4096;
        Bb[0][ks2][0] = *(const bf16x8*)(wp);
        Bb[0][ks2][1] = *(const bf16x8*)(wp + 256);
    }

    float amsg[2] = {0.f, 0.f};
    f32x16 acc[2][2];

#pragma unroll
    for (int h = 0; h < 8; ++h) {       // 8 half-kT phases; kT = h>>1
        const int kT = h >> 1;
        if ((h & 1) == 0) {
#pragma unroll
            for (int mt = 0; mt < 2; ++mt)
#pragma unroll
                for (int nt = 0; nt < 2; ++nt) acc[mt][nt] = (f32x16)(0.f);
        }
        __syncthreads();                // Hs[h&1] (built last phase) visible

        // load S-slices for half h+1 (sreg values are dead — consumed last phase)
        if (h < 7) {
#pragma unroll
            for (int s = 0; s < 4; ++s)
                sreg[s] = *(const u16x8*)&S2[((size_t)(((h + 1) * 4 + s) * 2048 + b * 64 + lane)) * 32 + w * 8];
        }

        // MFMA on Hs[h&1] (4 kc x 2 ks2, B one chunk ahead in regs)
#pragma unroll
        for (int kc = 0; kc < 4; ++kc) {
            const int j = h * 4 + kc;   // global W2t chunk 0..31
            const int cur = j & 1, nxt = cur ^ 1;
            if (j < 31) {
#pragma unroll
                for (int ks2 = 0; ks2 < 2; ++ks2) {
                    const u16* wp = Wb + (size_t)(j + 1) * 8192 + ks2 * 4096;
                    Bb[nxt][ks2][0] = *(const bf16x8*)(wp);
                    Bb[nxt][ks2][1] = *(const bf16x8*)(wp + 256);
                }
            }
#pragma unroll
            for (int ks2 = 0; ks2 < 2; ++ks2) {
                const int g = kc * 4 + ks2 * 2 + lh;
                bf16x8 A0 = *(const bf16x8*)&Hs[h & 1][g][l31][0];
                bf16x8 A1 = *(const bf16x8*)&Hs[h & 1][g][32 + l31][0];
                acc[0][0] = __builtin_amdgcn_mfma_f32_32x32x16_bf16(A0, Bb[cur][ks2][0], acc[0][0], 0, 0, 0);
                acc[0][1] = __builtin_amdgcn_mfma_f32_32x32x16_bf16(A0, Bb[cur][ks2][1], acc[0][1], 0, 0, 0);
                acc[1][0] = __builtin_amdgcn_mfma_f32_32x32x16_bf16(A1, Bb[cur][ks2][0], acc[1][0], 0, 0, 0);
                acc[1][1] = __builtin_amdgcn_mfma_f32_32x32x16_bf16(A1, Bb[cur][ks2][1], acc[1][1], 0, 0, 0);
            }
        }

        // build half h+1 into the OTHER buffer (overlaps with MFMA scheduling)
        if (h < 7) {
            const int kT1 = (h + 1) >> 1, hf1 = (h + 1) & 1;
#pragma unroll
            for (int s = 0; s < 4; ++s) {
                const float* rp = &Rf[kT1][(hf1 * 4 + s) * 32 + w * 8];
                f32x4 r0 = *(const f32x4*)rp, r1 = *(const f32x4*)(rp + 4);
                bf16x8 o;
#pragma unroll
                for (int e = 0; e < 4; ++e) {
                    o[e]     = (__bf16)fmaxf(r0[e] + bf2f(sreg[s][e]),     0.f);
                    o[4 + e] = (__bf16)fmaxf(r1[e] + bf2f(sreg[s][4 + e]), 0.f);
                }
                *(bf16x8*)&Hs[(h + 1) & 1][s * 4 + w][lane][0] = o;
            }
        }

        // per-kT epilogue at the odd half: bias + relu + rel_type row fold
        if (h & 1) {
#pragma unroll
            for (int nt = 0; nt < 2; ++nt) {
                const float bias = b2r[kT][nt];
#pragma unroll
                for (int mt = 0; mt < 2; ++mt) {
                    float s = 0.f;
#pragma unroll
                    for (int rq = 0; rq < 4; ++rq) {
                        f32x4 rt4 = *(const f32x4*)&rtS[kT][mt * 32 + rq * 8 + 4 * lh];
#pragma unroll
                        for (int e = 0; e < 4; ++e) {
                            float v = acc[mt][nt][rq * 4 + e] + bias;
                            v = v > 0.f ? v : 0.f;
                            s += rt4[e] * v;
                        }
                    }
                    amsg[nt] += s;
                }
            }
        }
    }

    // fold lh halves; unique writer per slot
#pragma unroll
    for (int nt = 0; nt < 2; ++nt) {
        float s = amsg[nt] + __shfl_xor(amsg[nt], 32);
        if (lh == 0)
            aggb[(size_t)(b * 64 + i) * 256 + w * 64 + nt * 32 + l31] = f2bf(s);
    }
}

// ---------------- output MLP: 256 blocks x 8 rows, barrier-free layers (R23-proven) ----------------
__global__ __launch_bounds__(256) void outmlp6_kernel(
    const float* __restrict__ x, const u16* __restrict__ aggb,
    const float* __restrict__ Wo1, const float* __restrict__ bo1,
    const float* __restrict__ Wo2, const float* __restrict__ bo2,
    const float* __restrict__ Wo3, const float* __restrict__ bo3,
    float* __restrict__ out)
{
    __shared__ u16 p1S[8 * 264];
    __shared__ u16 p2S[8 * 264];
    const int tid = threadIdx.x, lane = tid & 63, w = tid >> 6;   // w = n-quarter
    const int quad = lane >> 4, mloc = lane & 15;
    const int row0 = blockIdx.x * 8;
    const int arow = row0 + (mloc & 7);    // duplicated A row

    {   // ---- L1: K=384 (12 chunks), N=256, aug=[x|agg] ----
        f32x4 acc[4];
#pragma unroll
        for (int nt = 0; nt < 4; ++nt) acc[nt] = (f32x4){0.f, 0.f, 0.f, 0.f};
        for (int kk = 0; kk < 12; ++kk) {
            bf16x8 aF;
            if (kk < 4) {
                u16x8 t;
#pragma unroll
                for (int e = 0; e < 8; ++e) t[e] = f2bf(x[arow * 128 + kk * 32 + quad * 8 + e]);
                __builtin_memcpy(&aF, &t, 16);
            } else {
                aF = *(const bf16x8*)&aggb[(size_t)arow * 256 + (kk - 4) * 32 + quad * 8];
            }
#pragma unroll
            for (int nt = 0; nt < 4; ++nt) {
                const int n = w * 64 + nt * 16 + mloc;
                u16x8 t;
#pragma unroll
                for (int e = 0; e < 8; ++e)
                    t[e] = f2bf(Wo1[(kk * 32 + quad * 8 + e) * 256 + n]);
                bf16x8 bF;
                __builtin_memcpy(&bF, &t, 16);
                acc[nt] = __builtin_amdgcn_mfma_f32_16x16x32_bf16(aF, bF, acc[nt], 0, 0, 0);
            }
        }
#pragma unroll
        for (int nt = 0; nt < 4; ++nt) {
            const int n = w * 64 + nt * 16 + mloc;
            const float bias = bo1[n];
            if (quad < 2) {
#pragma unroll
                for (int r = 0; r < 4; ++r) {
                    float v = acc[nt][r] + bias;
                    p1S[(quad * 4 + r) * 264 + n] = f2bf(v > 0.f ? v : 0.f);
                }
            }
        }
    }
    LBAR();
    {   // ---- L2: K=256 (8 chunks), N=256 ----
        f32x4 acc[4];
#pragma unroll
        for (int nt = 0; nt < 4; ++nt) acc[nt] = (f32x4){0.f, 0.f, 0.f, 0.f};
        for (int kk = 0; kk < 8; ++kk) {
            bf16x8 aF = *(const bf16x8*)&p1S[(mloc & 7) * 264 + kk * 32 + quad * 8];
#pragma unroll
            for (int nt = 0; nt < 4; ++nt) {
                const int n = w * 64 + nt * 16 + mloc;
                u16x8 t;
#pragma unroll
                for (int e = 0; e < 8; ++e)
                    t[e] = f2bf(Wo2[(kk * 32 + quad * 8 + e) * 256 + n]);
                bf16x8 bF;
                __builtin_memcpy(&bF, &t, 16);
                acc[nt] = __builtin_amdgcn_mfma_f32_16x16x32_bf16(aF, bF, acc[nt], 0, 0, 0);
            }
        }
#pragma unroll
        for (int nt = 0; nt < 4; ++nt) {
            const int n = w * 64 + nt * 16 + mloc;
            const float bias = bo2[n];
            if (quad < 2) {
#pragma unroll
                for (int r = 0; r < 4; ++r) {
                    float v = acc[nt][r] + bias;
                    p2S[(quad * 4 + r) * 264 + n] = f2bf(v > 0.f ? v : 0.f);
                }
            }
        }
    }
    LBAR();
    {   // ---- L3: K=256 (8 chunks), N=128, residual ----
        f32x4 acc[2];
#pragma unroll
        for (int nt = 0; nt < 2; ++nt) acc[nt] = (f32x4){0.f, 0.f, 0.f, 0.f};
        for (int kk = 0; kk < 8; ++kk) {
            bf16x8 aF = *(const bf16x8*)&p2S[(mloc & 7) * 264 + kk * 32 + quad * 8];
#pragma unroll
            for (int nt = 0; nt < 2; ++nt) {
                const int n = w * 32 + nt * 16 + mloc;
                u16x8 t;
#pragma unroll
                for (int e = 0; e < 8; ++e)
                    t[e] = f2bf(Wo3[(kk * 32 + quad * 8 + e) * 128 + n]);
                bf16x8 bF;
                __builtin_memcpy(&bF, &t, 16);
                acc[nt] = __builtin_amdgcn_mfma_f32_16x16x32_bf16(aF, bF, acc[nt], 0, 0, 0);
            }
        }
#pragma unroll
        for (int nt = 0; nt < 2; ++nt) {
            const int n = w * 32 + nt * 16 + mloc;
            const float bias = bo3[n];
            if (quad < 2) {
#pragma unroll
                for (int r = 0; r < 4; ++r) {
                    const int grow = row0 + quad * 4 + r;
                    out[grow * 128 + n] = x[grow * 128 + n] + acc[nt][r] + bias;
                }
            }
        }
    }
}

extern "C" void kernel_launch(void* const* d_in, const int* in_sizes, int n_in,
                              void* d_out, int out_size, void* d_ws, size_t ws_size,
                              hipStream_t stream) {
    const float* x   = (const float*)d_in[0];
    const float* rel = (const float*)d_in[1];
    const float* W1  = (const float*)d_in[4];
    const float* b1  = (const float*)d_in[5];
    const float* W2  = (const float*)d_in[6];
    const float* b2  = (const float*)d_in[7];
    const float* Wo1 = (const float*)d_in[8];
    const float* bo1 = (const float*)d_in[9];
    const float* Wo2 = (const float*)d_in[10];
    const float* bo2 = (const float*)d_in[11];
    const float* Wo3 = (const float*)d_in[12];
    const float* bo3 = (const float*)d_in[13];
    float* out = (float*)d_out;

    char* ws = (char*)d_ws;
    u16* W2t  = (u16*)(ws + WS_W2T);
    u16* R    = (u16*)(ws + WS_R);
    u16* S2   = (u16*)(ws + WS_S);
    u16* aggb = (u16*)(ws + WS_AGG);

    prep_rs_kernel<<<2048, 256, 0, stream>>>(W2, x, W1, b1, W2t, R, S2);
    edge14_kernel<<<2048, 256, 0, stream>>>(R, S2, rel, W2t, b2, aggb);
    outmlp6_kernel<<<256, 256, 0, stream>>>(x, aggb, Wo1, bo1, Wo2, bo2, Wo3, bo3, out);
}

// Round 16
// 196.711 us; speedup vs baseline: 1.3098x; 1.3098x over previous
//
#include <hip/hip_runtime.h>

// GraphDecoder (NRI) — round 25: edge15 = edge14's half-kT dbuf schedule with
// the two R24 spill bugs fixed (WRITE 312MB -> scratch, cause by inspection):
//  (1) h-loop was fully unrolled -> liveness explosion. Now runtime loop
//      (#pragma unroll 1); inner loops stay unrolled. Bb parity stays STATIC:
//      cur = (h*4+kc)&1 = kc&1 since h*4 is even.
//  (2) b2r[kT] runtime-indexed reg array -> scratch (rule #20). Now b2 loaded
//      from global in the epilogue (edge12-proven at 85.4us).
// Dbuf race analysis unchanged (phase h reads buf[h&1], writes buf[(h+1)&1],
// top-of-phase barrier orders reuse). prep/outmlp6 byte-identical to R23.
// B=32, N=64, F=128, K=4, H=M=NH=256, E=4032.

#define B_ 32
#define N_ 64
#define F_ 128
#define K_ 4
#define E_ 4032

// ws layout (bytes): total 9,961,472 <= proven 9,994,240
#define WS_W2T 0u
#define WS_R   524288u
#define WS_S   4718592u
#define WS_AGG 8912896u

typedef unsigned short u16;
typedef u16    u16x4  __attribute__((ext_vector_type(4)));
typedef u16    u16x8  __attribute__((ext_vector_type(8)));
typedef __bf16 bf16x8 __attribute__((ext_vector_type(8)));
typedef float  f32x4  __attribute__((ext_vector_type(4)));
typedef float  f32x16 __attribute__((ext_vector_type(16)));

__device__ __forceinline__ u16 f2bf(float f) {
    unsigned u; __builtin_memcpy(&u, &f, 4);
    return (u16)((u + 0x7FFFu + ((u >> 16) & 1u)) >> 16);
}
__device__ __forceinline__ float bf2f(u16 u) {
    unsigned v = ((unsigned)u) << 16;
    float f; __builtin_memcpy(&f, &v, 4); return f;
}

// raw barrier (LDS-only handoff; keeps vmem prefetch in flight)
#define LBAR() do { \
    asm volatile("s_waitcnt lgkmcnt(0)" ::: "memory"); \
    __builtin_amdgcn_s_barrier(); \
    __builtin_amdgcn_sched_barrier(0); \
} while (0)

// ---------------- fused prep (W2 -> cf bf16 chunks) + R/S2 tables (R23-proven) ----------------
// S2 kk-chunked: S2[((k*8+kc)*2048 + b*64 + row)*32 + kk_local]  (kc = kk>>5)
__global__ __launch_bounds__(256) void prep_rs_kernel(
    const float* __restrict__ W2, const float* __restrict__ x,
    const float* __restrict__ W1, const float* __restrict__ b1,
    u16* __restrict__ W2t, u16* __restrict__ R, u16* __restrict__ S)
{
    __shared__ u16 ldsA[64 * 136];
    __shared__ u16 ldsW[32 * 136];
    const int tid = threadIdx.x;

    if (blockIdx.x < 1024) {
        // linear read of W2 (coalesced); scattered 2B writes (fire-and-forget).
        unsigned gid = blockIdx.x * 256u + tid;
        unsigned n = gid & 255u, kk = (gid >> 8) & 255u, k = gid >> 16;
        unsigned dst = (k * 8u + (kk >> 5)) * 8192u
                     + ((((kk >> 4) & 1u) * 2u) + ((kk >> 3) & 1u)) * 2048u
                     + n * 8u + (kk & 7u);
        W2t[dst] = f2bf(W2[gid]);
        return;
    }

    // part 2: R/S tables. 1024 blocks: (k, half, b) x ch4; ch covers 2 c-chunks.
    const int lane = tid & 63, w = tid >> 6;
    const int quad = lane >> 4, mloc = lane & 15;
    const int bx = blockIdx.x - 1024;
    const int ch = bx & 3;
    const int bq = bx >> 2;
    const int k = bq >> 6, half = (bq >> 5) & 1, b = bq & 31;

    for (int idx = tid; idx < 2048; idx += 256) {
        int row = idx >> 5, c4 = idx & 31;
        f32x4 v = *(const f32x4*)&x[(b * 64 + row) * 128 + c4 * 4];
        u16x4 o;
#pragma unroll
        for (int e = 0; e < 4; ++e) o[e] = f2bf(v[e]);
        *(u16x4*)&ldsA[row * 136 + c4 * 4] = o;
    }
    __syncthreads();

    bf16x8 aF[4];
#pragma unroll
    for (int ks = 0; ks < 4; ++ks)
        aF[ks] = *(const bf16x8*)&ldsA[(w * 16 + mloc) * 136 + quad * 8 + ks * 32];

    u16* dst = half ? S : R;
    for (int c = ch * 2; c < ch * 2 + 2; ++c) {
        __syncthreads();
        for (int idx = tid; idx < 4096; idx += 256) {
            int n = idx & 31, f = idx >> 5;
            ldsW[n * 136 + f] = f2bf(W1[(k * 256 + half * 128 + f) * 256 + c * 32 + n]);
        }
        __syncthreads();
#pragma unroll
        for (int nt = 0; nt < 2; ++nt) {
            f32x4 acc = (f32x4){0.f, 0.f, 0.f, 0.f};
            const int boff = (nt * 16 + mloc) * 136 + quad * 8;
#pragma unroll
            for (int ks = 0; ks < 4; ++ks)
                acc = __builtin_amdgcn_mfma_f32_16x16x32_bf16(
                    aF[ks], *(const bf16x8*)&ldsW[boff + ks * 32], acc, 0, 0, 0);
            const int n = c * 32 + nt * 16 + mloc;
            const float bias = half ? 0.f : b1[k * 256 + n];
#pragma unroll
            for (int r = 0; r < 4; ++r) {
                int row = w * 16 + quad * 4 + r;
                if (half) {
                    dst[((size_t)((k * 8 + c) * 2048 + b * 64 + row)) * 32 + nt * 16 + mloc]
                        = f2bf(acc[r] + bias);
                } else {
                    dst[((size_t)(k * 2048 + b * 64 + row)) * 256 + n] = f2bf(acc[r] + bias);
                }
            }
        }
    }
}

// ---------------- edge kernel: half-kT dbuf Hs, runtime phase loop ----------------
__global__ __launch_bounds__(256, 3) void edge15_kernel(
    const u16* __restrict__ R, const u16* __restrict__ S2,
    const float* __restrict__ rel, const u16* __restrict__ W2t,
    const float* __restrict__ b2, u16* __restrict__ aggb)
{
    __shared__ u16   Hs[2][16][64][8];  // 2 x 16KB half-kT buffers (32KB total)
    __shared__ float Rf[4][256];        // receiver R rows, f32 — written once
    __shared__ float rtS[4][64];        // rel_type [k][j], self=0 — written once

    const int tid  = threadIdx.x;
    const int lane = tid & 63;
    const int w    = tid >> 6;          // n-quarter (MFMA) AND kk32-subgroup (build)
    const int l31  = lane & 31;
    const int lh   = lane >> 5;
    const int bid  = ((blockIdx.x & 7) << 8) | (blockIdx.x >> 3);
    const int b    = bid >> 6;
    const int i    = bid & 63;          // receiver node

    {
        const int k = tid >> 6, j = tid & 63;
        float v = 0.f;
        if (j != i) v = rel[((size_t)(b * E_) + i * 63 + (j - (j > i))) * 4 + k];
        rtS[k][j] = v;
    }
    {
        const int k = tid >> 6, e4 = tid & 63;
        u16x4 t4 = *(const u16x4*)&R[((size_t)(k * 2048 + b * 64 + i)) * 256 + e4 * 4];
#pragma unroll
        for (int e = 0; e < 4; ++e) Rf[k][e4 * 4 + e] = bf2f(t4[e]);
    }

    // sreg: 4 slots for the NEXT half-kT to build (reloaded in place each phase)
    u16x8 sreg[4];
#pragma unroll
    for (int s = 0; s < 4; ++s)
        sreg[s] = *(const u16x8*)&S2[((size_t)(s * 2048 + b * 64 + lane)) * 32 + w * 8];

    __syncthreads();

    // build half 0 into Hs[0]
#pragma unroll
    for (int s = 0; s < 4; ++s) {
        const float* rp = &Rf[0][s * 32 + w * 8];
        f32x4 r0 = *(const f32x4*)rp, r1 = *(const f32x4*)(rp + 4);
        bf16x8 o;
#pragma unroll
        for (int e = 0; e < 4; ++e) {
            o[e]     = (__bf16)fmaxf(r0[e] + bf2f(sreg[s][e]),     0.f);
            o[4 + e] = (__bf16)fmaxf(r1[e] + bf2f(sreg[s][4 + e]), 0.f);
        }
        *(bf16x8*)&Hs[0][s * 4 + w][lane][0] = o;
    }

    const u16* Wb = W2t + lh * 2048 + (w * 64 + l31) * 8;
    bf16x8 Bb[2][2][2];   // [chunk parity][ks2][nt] — static indices (cur = kc&1)
#pragma unroll
    for (int ks2 = 0; ks2 < 2; ++ks2) {
        const u16* wp = Wb + ks2 * 4096;
        Bb[0][ks2][0] = *(const bf16x8*)(wp);
        Bb[0][ks2][1] = *(const bf16x8*)(wp + 256);
    }

    float amsg[2] = {0.f, 0.f};
    f32x16 acc[2][2];

#pragma unroll 1
    for (int h = 0; h < 8; ++h) {       // runtime phase loop; kT = h>>1
        const int kT = h >> 1;
        if ((h & 1) == 0) {
#pragma unroll
            for (int mt = 0; mt < 2; ++mt)
#pragma unroll
                for (int nt = 0; nt < 2; ++nt) acc[mt][nt] = (f32x16)(0.f);
        }
        __syncthreads();                // Hs[h&1] (built last phase) visible

        // load S-slices for half h+1 (sreg values are dead — consumed last phase)
        if (h < 7) {
#pragma unroll
            for (int s = 0; s < 4; ++s)
                sreg[s] = *(const u16x8*)&S2[((size_t)(((h + 1) * 4 + s) * 2048 + b * 64 + lane)) * 32 + w * 8];
        }

        // MFMA on Hs[h&1] (4 kc x 2 ks2, B one chunk ahead in regs)
        const u16(*hsr)[64][8] = Hs[h & 1];
#pragma unroll
        for (int kc = 0; kc < 4; ++kc) {
            const int cur = kc & 1, nxt = cur ^ 1;   // (h*4+kc)&1 == kc&1
            if (h * 4 + kc < 31) {
#pragma unroll
                for (int ks2 = 0; ks2 < 2; ++ks2) {
                    const u16* wp = Wb + (size_t)(h * 4 + kc + 1) * 8192 + ks2 * 4096;
                    Bb[nxt][ks2][0] = *(const bf16x8*)(wp);
                    Bb[nxt][ks2][1] = *(const bf16x8*)(wp + 256);
                }
            }
#pragma unroll
            for (int ks2 = 0; ks2 < 2; ++ks2) {
                const int g = kc * 4 + ks2 * 2 + lh;
                bf16x8 A0 = *(const bf16x8*)&hsr[g][l31][0];
                bf16x8 A1 = *(const bf16x8*)&hsr[g][32 + l31][0];
                acc[0][0] = __builtin_amdgcn_mfma_f32_32x32x16_bf16(A0, Bb[cur][ks2][0], acc[0][0], 0, 0, 0);
                acc[0][1] = __builtin_amdgcn_mfma_f32_32x32x16_bf16(A0, Bb[cur][ks2][1], acc[0][1], 0, 0, 0);
                acc[1][0] = __builtin_amdgcn_mfma_f32_32x32x16_bf16(A1, Bb[cur][ks2][0], acc[1][0], 0, 0, 0);
                acc[1][1] = __builtin_amdgcn_mfma_f32_32x32x16_bf16(A1, Bb[cur][ks2][1], acc[1][1], 0, 0, 0);
            }
        }

        // build half h+1 into the OTHER buffer (schedules into the MFMA shadow)
        if (h < 7) {
            const int kT1 = (h + 1) >> 1, hf1 = (h + 1) & 1;
#pragma unroll
            for (int s = 0; s < 4; ++s) {
                const float* rp = &Rf[kT1][(hf1 * 4 + s) * 32 + w * 8];
                f32x4 r0 = *(const f32x4*)rp, r1 = *(const f32x4*)(rp + 4);
                bf16x8 o;
#pragma unroll
                for (int e = 0; e < 4; ++e) {
                    o[e]     = (__bf16)fmaxf(r0[e] + bf2f(sreg[s][e]),     0.f);
                    o[4 + e] = (__bf16)fmaxf(r1[e] + bf2f(sreg[s][4 + e]), 0.f);
                }
                *(bf16x8*)&Hs[(h + 1) & 1][s * 4 + w][lane][0] = o;
            }
        }

        // per-kT epilogue at the odd half (bias from global, edge12-proven)
        if (h & 1) {
#pragma unroll
            for (int nt = 0; nt < 2; ++nt) {
                const float bias = b2[kT * 256 + w * 64 + nt * 32 + l31];
#pragma unroll
                for (int mt = 0; mt < 2; ++mt) {
                    float s = 0.f;
#pragma unroll
                    for (int rq = 0; rq < 4; ++rq) {
                        f32x4 rt4 = *(const f32x4*)&rtS[kT][mt * 32 + rq * 8 + 4 * lh];
#pragma unroll
                        for (int e = 0; e < 4; ++e) {
                            float v = acc[mt][nt][rq * 4 + e] + bias;
                            v = v > 0.f ? v : 0.f;
                            s += rt4[e] * v;
                        }
                    }
                    amsg[nt] += s;
                }
            }
        }
    }

    // fold lh halves; unique writer per slot
#pragma unroll
    for (int nt = 0; nt < 2; ++nt) {
        float s = amsg[nt] + __shfl_xor(amsg[nt], 32);
        if (lh == 0)
            aggb[(size_t)(b * 64 + i) * 256 + w * 64 + nt * 32 + l31] = f2bf(s);
    }
}

// ---------------- output MLP: 256 blocks x 8 rows, barrier-free layers (R23-proven) ----------------
__global__ __launch_bounds__(256) void outmlp6_kernel(
    const float* __restrict__ x, const u16* __restrict__ aggb,
    const float* __restrict__ Wo1, const float* __restrict__ bo1,
    const float* __restrict__ Wo2, const float* __restrict__ bo2,
    const float* __restrict__ Wo3, const float* __restrict__ bo3,
    float* __restrict__ out)
{
    __shared__ u16 p1S[8 * 264];
    __shared__ u16 p2S[8 * 264];
    const int tid = threadIdx.x, lane = tid & 63, w = tid >> 6;   // w = n-quarter
    const int quad = lane >> 4, mloc = lane & 15;
    const int row0 = blockIdx.x * 8;
    const int arow = row0 + (mloc & 7);    // duplicated A row

    {   // ---- L1: K=384 (12 chunks), N=256, aug=[x|agg] ----
        f32x4 acc[4];
#pragma unroll
        for (int nt = 0; nt < 4; ++nt) acc[nt] = (f32x4){0.f, 0.f, 0.f, 0.f};
        for (int kk = 0; kk < 12; ++kk) {
            bf16x8 aF;
            if (kk < 4) {
                u16x8 t;
#pragma unroll
                for (int e = 0; e < 8; ++e) t[e] = f2bf(x[arow * 128 + kk * 32 + quad * 8 + e]);
                __builtin_memcpy(&aF, &t, 16);
            } else {
                aF = *(const bf16x8*)&aggb[(size_t)arow * 256 + (kk - 4) * 32 + quad * 8];
            }
#pragma unroll
            for (int nt = 0; nt < 4; ++nt) {
                const int n = w * 64 + nt * 16 + mloc;
                u16x8 t;
#pragma unroll
                for (int e = 0; e < 8; ++e)
                    t[e] = f2bf(Wo1[(kk * 32 + quad * 8 + e) * 256 + n]);
                bf16x8 bF;
                __builtin_memcpy(&bF, &t, 16);
                acc[nt] = __builtin_amdgcn_mfma_f32_16x16x32_bf16(aF, bF, acc[nt], 0, 0, 0);
            }
        }
#pragma unroll
        for (int nt = 0; nt < 4; ++nt) {
            const int n = w * 64 + nt * 16 + mloc;
            const float bias = bo1[n];
            if (quad < 2) {
#pragma unroll
                for (int r = 0; r < 4; ++r) {
                    float v = acc[nt][r] + bias;
                    p1S[(quad * 4 + r) * 264 + n] = f2bf(v > 0.f ? v : 0.f);
                }
            }
        }
    }
    LBAR();
    {   // ---- L2: K=256 (8 chunks), N=256 ----
        f32x4 acc[4];
#pragma unroll
        for (int nt = 0; nt < 4; ++nt) acc[nt] = (f32x4){0.f, 0.f, 0.f, 0.f};
        for (int kk = 0; kk < 8; ++kk) {
            bf16x8 aF = *(const bf16x8*)&p1S[(mloc & 7) * 264 + kk * 32 + quad * 8];
#pragma unroll
            for (int nt = 0; nt < 4; ++nt) {
                const int n = w * 64 + nt * 16 + mloc;
                u16x8 t;
#pragma unroll
                for (int e = 0; e < 8; ++e)
                    t[e] = f2bf(Wo2[(kk * 32 + quad * 8 + e) * 256 + n]);
                bf16x8 bF;
                __builtin_memcpy(&bF, &t, 16);
                acc[nt] = __builtin_amdgcn_mfma_f32_16x16x32_bf16(aF, bF, acc[nt], 0, 0, 0);
            }
        }
#pragma unroll
        for (int nt = 0; nt < 4; ++nt) {
            const int n = w * 64 + nt * 16 + mloc;
            const float bias = bo2[n];
            if (quad < 2) {
#pragma unroll
                for (int r = 0; r < 4; ++r) {
                    float v = acc[nt][r] + bias;
                    p2S[(quad * 4 + r) * 264 + n] = f2bf(v > 0.f ? v : 0.f);
                }
            }
        }
    }
    LBAR();
    {   // ---- L3: K=256 (8 chunks), N=128, residual ----
        f32x4 acc[2];
#pragma unroll
        for (int nt = 0; nt < 2; ++nt) acc[nt] = (f32x4){0.f, 0.f, 0.f, 0.f};
        for (int kk = 0; kk < 8; ++kk) {
            bf16x8 aF = *(const bf16x8*)&p2S[(mloc & 7) * 264 + kk * 32 + quad * 8];
#pragma unroll
            for (int nt = 0; nt < 2; ++nt) {
                const int n = w * 32 + nt * 16 + mloc;
                u16x8 t;
#pragma unroll
                for (int e = 0; e < 8; ++e)
                    t[e] = f2bf(Wo3[(kk * 32 + quad * 8 + e) * 128 + n]);
                bf16x8 bF;
                __builtin_memcpy(&bF, &t, 16);
                acc[nt] = __builtin_amdgcn_mfma_f32_16x16x32_bf16(aF, bF, acc[nt], 0, 0, 0);
            }
        }
#pragma unroll
        for (int nt = 0; nt < 2; ++nt) {
            const int n = w * 32 + nt * 16 + mloc;
            const float bias = bo3[n];
            if (quad < 2) {
#pragma unroll
                for (int r = 0; r < 4; ++r) {
                    const int grow = row0 + quad * 4 + r;
                    out[grow * 128 + n] = x[grow * 128 + n] + acc[nt][r] + bias;
                }
            }
        }
    }
}

extern "C" void kernel_launch(void* const* d_in, const int* in_sizes, int n_in,
                              void* d_out, int out_size, void* d_ws, size_t ws_size,
                              hipStream_t stream) {
    const float* x   = (const float*)d_in[0];
    const float* rel = (const float*)d_in[1];
    const float* W1  = (const float*)d_in[4];
    const float* b1  = (const float*)d_in[5];
    const float* W2  = (const float*)d_in[6];
    const float* b2  = (const float*)d_in[7];
    const float* Wo1 = (const float*)d_in[8];
    const float* bo1 = (const float*)d_in[9];
    const float* Wo2 = (const float*)d_in[10];
    const float* bo2 = (const float*)d_in[11];
    const float* Wo3 = (const float*)d_in[12];
    const float* bo3 = (const float*)d_in[13];
    float* out = (float*)d_out;

    char* ws = (char*)d_ws;
    u16* W2t  = (u16*)(ws + WS_W2T);
    u16* R    = (u16*)(ws + WS_R);
    u16* S2   = (u16*)(ws + WS_S);
    u16* aggb = (u16*)(ws + WS_AGG);

    prep_rs_kernel<<<2048, 256, 0, stream>>>(W2, x, W1, b1, W2t, R, S2);
    edge15_kernel<<<2048, 256, 0, stream>>>(R, S2, rel, W2t, b2, aggb);
    outmlp6_kernel<<<256, 256, 0, stream>>>(x, aggb, Wo1, bo1, Wo2, bo2, Wo3, bo3, out);
}

// Round 17
// 190.095 us; speedup vs baseline: 1.3554x; 1.0348x over previous
//
#include <hip/hip_runtime.h>

// GraphDecoder (NRI) — round 26: revert to R23 (192.2us proven best; R24/R25
// half-kT dbuf closed: spill-free variant still 101us vs edge12's 87 — finer
// phases lose more to per-phase overhead than they hide, reg budget saturated).
// ONE change vs R23: prep grid 2048 -> 1024 by inlining the W2t conversion
// (256 elems/block, identical gid mapping) into the R/S blocks — prep is
// latency-bound; 1024 blocks = ~1.33 scheduling rounds vs ~2.7.
// edge12 / outmlp6 byte-identical to R23. B=32,N=64,F=128,K=4,E=4032.

#define B_ 32
#define N_ 64
#define F_ 128
#define K_ 4
#define E_ 4032

// ws layout (bytes): total 9,961,472 <= proven 9,994,240
#define WS_W2T 0u
#define WS_R   524288u
#define WS_S   4718592u
#define WS_AGG 8912896u

typedef unsigned short u16;
typedef u16    u16x4  __attribute__((ext_vector_type(4)));
typedef u16    u16x8  __attribute__((ext_vector_type(8)));
typedef __bf16 bf16x8 __attribute__((ext_vector_type(8)));
typedef float  f32x4  __attribute__((ext_vector_type(4)));
typedef float  f32x16 __attribute__((ext_vector_type(16)));

__device__ __forceinline__ u16 f2bf(float f) {
    unsigned u; __builtin_memcpy(&u, &f, 4);
    return (u16)((u + 0x7FFFu + ((u >> 16) & 1u)) >> 16);
}
__device__ __forceinline__ float bf2f(u16 u) {
    unsigned v = ((unsigned)u) << 16;
    float f; __builtin_memcpy(&f, &v, 4); return f;
}

// raw barrier (LDS-only handoff; keeps vmem prefetch in flight)
#define LBAR() do { \
    asm volatile("s_waitcnt lgkmcnt(0)" ::: "memory"); \
    __builtin_amdgcn_s_barrier(); \
    __builtin_amdgcn_sched_barrier(0); \
} while (0)

// ---------------- fused prep: W2t conversion inlined + R/S2 tables ----------------
// 1024 blocks; each does 256 W2t elems (1/thread, same mapping as R23) then
// its (k, half, b, ch) R/S slice (ch covers 2 c-chunks).
// S2 kk-chunked: S2[((k*8+kc)*2048 + b*64 + row)*32 + kk_local]  (kc = kk>>5)
__global__ __launch_bounds__(256) void prep_rs_kernel(
    const float* __restrict__ W2, const float* __restrict__ x,
    const float* __restrict__ W1, const float* __restrict__ b1,
    u16* __restrict__ W2t, u16* __restrict__ R, u16* __restrict__ S)
{
    __shared__ u16 ldsA[64 * 136];
    __shared__ u16 ldsW[32 * 136];
    const int tid = threadIdx.x;

    {   // W2t: linear coalesced read, scattered 2B write (fire-and-forget)
        unsigned gid = blockIdx.x * 256u + tid;
        unsigned n = gid & 255u, kk = (gid >> 8) & 255u, k = gid >> 16;
        unsigned dst = (k * 8u + (kk >> 5)) * 8192u
                     + ((((kk >> 4) & 1u) * 2u) + ((kk >> 3) & 1u)) * 2048u
                     + n * 8u + (kk & 7u);
        W2t[dst] = f2bf(W2[gid]);
    }

    // R/S tables: (k, half, b) x ch4; ch covers 2 c-chunks.
    const int lane = tid & 63, w = tid >> 6;
    const int quad = lane >> 4, mloc = lane & 15;
    const int bx = blockIdx.x;
    const int ch = bx & 3;
    const int bq = bx >> 2;
    const int k = bq >> 6, half = (bq >> 5) & 1, b = bq & 31;

    for (int idx = tid; idx < 2048; idx += 256) {
        int row = idx >> 5, c4 = idx & 31;
        f32x4 v = *(const f32x4*)&x[(b * 64 + row) * 128 + c4 * 4];
        u16x4 o;
#pragma unroll
        for (int e = 0; e < 4; ++e) o[e] = f2bf(v[e]);
        *(u16x4*)&ldsA[row * 136 + c4 * 4] = o;
    }
    __syncthreads();

    bf16x8 aF[4];
#pragma unroll
    for (int ks = 0; ks < 4; ++ks)
        aF[ks] = *(const bf16x8*)&ldsA[(w * 16 + mloc) * 136 + quad * 8 + ks * 32];

    u16* dst = half ? S : R;
    for (int c = ch * 2; c < ch * 2 + 2; ++c) {
        __syncthreads();
        for (int idx = tid; idx < 4096; idx += 256) {
            int n = idx & 31, f = idx >> 5;
            ldsW[n * 136 + f] = f2bf(W1[(k * 256 + half * 128 + f) * 256 + c * 32 + n]);
        }
        __syncthreads();
#pragma unroll
        for (int nt = 0; nt < 2; ++nt) {
            f32x4 acc = (f32x4){0.f, 0.f, 0.f, 0.f};
            const int boff = (nt * 16 + mloc) * 136 + quad * 8;
#pragma unroll
            for (int ks = 0; ks < 4; ++ks)
                acc = __builtin_amdgcn_mfma_f32_16x16x32_bf16(
                    aF[ks], *(const bf16x8*)&ldsW[boff + ks * 32], acc, 0, 0, 0);
            const int n = c * 32 + nt * 16 + mloc;
            const float bias = half ? 0.f : b1[k * 256 + n];
#pragma unroll
            for (int r = 0; r < 4; ++r) {
                int row = w * 16 + quad * 4 + r;
                if (half) {
                    dst[((size_t)((k * 8 + c) * 2048 + b * 64 + row)) * 32 + nt * 16 + mloc]
                        = f2bf(acc[r] + bias);
                } else {
                    dst[((size_t)(k * 2048 + b * 64 + row)) * 256 + n] = f2bf(acc[r] + bias);
                }
            }
        }
    }
}

// ---------------- edge kernel: per-kT staged H + 2-slot reg pipelining (R23-proven) ----------------
__global__ __launch_bounds__(256, 3) void edge12_kernel(
    const u16* __restrict__ R, const u16* __restrict__ S2,
    const float* __restrict__ rel, const u16* __restrict__ W2t,
    const float* __restrict__ b2, u16* __restrict__ aggb)
{
    __shared__ u16   Hs[32][64][8];   // H tile for one kT: [g=kk-group][row][8kk] — 32KB
    __shared__ float Rf[4][256];      // receiver R rows, f32 — written once
    __shared__ float rtS[4][64];      // rel_type [k][j], self=0 — written once

    const int tid  = threadIdx.x;
    const int lane = tid & 63;
    const int w    = tid >> 6;        // n-quarter (MFMA) AND kk32-subgroup (build)
    const int l31  = lane & 31;
    const int lh   = lane >> 5;
    const int bid  = ((blockIdx.x & 7) << 8) | (blockIdx.x >> 3);
    const int b    = bid >> 6;
    const int i    = bid & 63;        // receiver node

    {
        const int k = tid >> 6, j = tid & 63;
        float v = 0.f;
        if (j != i) v = rel[((size_t)(b * E_) + i * 63 + (j - (j > i))) * 4 + k];
        rtS[k][j] = v;
    }
    {
        const int k = tid >> 6, e4 = tid & 63;
        u16x4 t4 = *(const u16x4*)&R[((size_t)(k * 2048 + b * 64 + i)) * 256 + e4 * 4];
#pragma unroll
        for (int e = 0; e < 4; ++e) Rf[k][e4 * 4 + e] = bf2f(t4[e]);
    }

    u16x8 sreg[8];
#pragma unroll
    for (int s = 0; s < 8; ++s)
        sreg[s] = *(const u16x8*)&S2[((size_t)(s * 2048 + b * 64 + lane)) * 32 + w * 8];

    __syncthreads();

    const u16* Wb = W2t + lh * 2048 + (w * 64 + l31) * 8;

    float amsg[2] = {0.f, 0.f};

    for (int kT = 0; kT < 4; ++kT) {
        bf16x8 Bb[2][2][2];   // [kc parity][ks2][nt] — all indices static
#pragma unroll
        for (int ks2 = 0; ks2 < 2; ++ks2) {
            const u16* wp = Wb + (size_t)(kT * 8) * 8192 + ks2 * 4096;
            Bb[0][ks2][0] = *(const bf16x8*)(wp);
            Bb[0][ks2][1] = *(const bf16x8*)(wp + 256);
        }
        // ---- build H(kT) from sreg: pure VALU, conflict-free writes ----
#pragma unroll
        for (int s = 0; s < 8; ++s) {
            const float* rp = &Rf[kT][s * 32 + w * 8];
            f32x4 r0 = *(const f32x4*)rp, r1 = *(const f32x4*)(rp + 4);
            bf16x8 o;
#pragma unroll
            for (int e = 0; e < 4; ++e) {
                o[e]     = (__bf16)fmaxf(r0[e] + bf2f(sreg[s][e]),     0.f);
                o[4 + e] = (__bf16)fmaxf(r1[e] + bf2f(sreg[s][4 + e]), 0.f);
            }
            *(bf16x8*)&Hs[s * 4 + w][lane][0] = o;
        }
        __syncthreads();   // H(kT) visible

        f32x16 acc[2][2];
#pragma unroll
        for (int mt = 0; mt < 2; ++mt)
#pragma unroll
            for (int nt = 0; nt < 2; ++nt) acc[mt][nt] = (f32x16)(0.f);

#pragma unroll
        for (int kc = 0; kc < 8; ++kc) {
            const int cur = kc & 1, nxt = cur ^ 1;
            // reload sreg for kT+1 (regs dead after the build consumed them)
            if (kc == 0 && kT < 3) {
#pragma unroll
                for (int s = 0; s < 8; ++s)
                    sreg[s] = *(const u16x8*)&S2[((size_t)(((kT + 1) * 8 + s) * 2048 + b * 64 + lane)) * 32 + w * 8];
            }
            // prefetch B(kc+1)
            if (kc < 7) {
#pragma unroll
                for (int ks2 = 0; ks2 < 2; ++ks2) {
                    const u16* wp = Wb + (size_t)(kT * 8 + kc + 1) * 8192 + ks2 * 4096;
                    Bb[nxt][ks2][0] = *(const bf16x8*)(wp);
                    Bb[nxt][ks2][1] = *(const bf16x8*)(wp + 256);
                }
            }
#pragma unroll
            for (int ks2 = 0; ks2 < 2; ++ks2) {
                const int g = kc * 4 + ks2 * 2 + lh;
                bf16x8 A0 = *(const bf16x8*)&Hs[g][l31][0];
                bf16x8 A1 = *(const bf16x8*)&Hs[g][32 + l31][0];
                acc[0][0] = __builtin_amdgcn_mfma_f32_32x32x16_bf16(A0, Bb[cur][ks2][0], acc[0][0], 0, 0, 0);
                acc[0][1] = __builtin_amdgcn_mfma_f32_32x32x16_bf16(A0, Bb[cur][ks2][1], acc[0][1], 0, 0, 0);
                acc[1][0] = __builtin_amdgcn_mfma_f32_32x32x16_bf16(A1, Bb[cur][ks2][0], acc[1][0], 0, 0, 0);
                acc[1][1] = __builtin_amdgcn_mfma_f32_32x32x16_bf16(A1, Bb[cur][ks2][1], acc[1][1], 0, 0, 0);
            }
        }

#pragma unroll
        for (int nt = 0; nt < 2; ++nt) {
            const float bias = b2[kT * 256 + w * 64 + nt * 32 + l31];
#pragma unroll
            for (int mt = 0; mt < 2; ++mt) {
                float s = 0.f;
#pragma unroll
                for (int rq = 0; rq < 4; ++rq) {
                    f32x4 rt4 = *(const f32x4*)&rtS[kT][mt * 32 + rq * 8 + 4 * lh];
#pragma unroll
                    for (int e = 0; e < 4; ++e) {
                        float v = acc[mt][nt][rq * 4 + e] + bias;
                        v = v > 0.f ? v : 0.f;
                        s += rt4[e] * v;
                    }
                }
                amsg[nt] += s;
            }
        }
        __syncthreads();
    }

#pragma unroll
    for (int nt = 0; nt < 2; ++nt) {
        float s = amsg[nt] + __shfl_xor(amsg[nt], 32);
        if (lh == 0)
            aggb[(size_t)(b * 64 + i) * 256 + w * 64 + nt * 32 + l31] = f2bf(s);
    }
}

// ---------------- output MLP: 256 blocks x 8 rows, barrier-free layers (R23-proven) ----------------
__global__ __launch_bounds__(256) void outmlp6_kernel(
    const float* __restrict__ x, const u16* __restrict__ aggb,
    const float* __restrict__ Wo1, const float* __restrict__ bo1,
    const float* __restrict__ Wo2, const float* __restrict__ bo2,
    const float* __restrict__ Wo3, const float* __restrict__ bo3,
    float* __restrict__ out)
{
    __shared__ u16 p1S[8 * 264];
    __shared__ u16 p2S[8 * 264];
    const int tid = threadIdx.x, lane = tid & 63, w = tid >> 6;   // w = n-quarter
    const int quad = lane >> 4, mloc = lane & 15;
    const int row0 = blockIdx.x * 8;
    const int arow = row0 + (mloc & 7);    // duplicated A row

    {   // ---- L1: K=384 (12 chunks), N=256, aug=[x|agg] ----
        f32x4 acc[4];
#pragma unroll
        for (int nt = 0; nt < 4; ++nt) acc[nt] = (f32x4){0.f, 0.f, 0.f, 0.f};
        for (int kk = 0; kk < 12; ++kk) {
            bf16x8 aF;
            if (kk < 4) {
                u16x8 t;
#pragma unroll
                for (int e = 0; e < 8; ++e) t[e] = f2bf(x[arow * 128 + kk * 32 + quad * 8 + e]);
                __builtin_memcpy(&aF, &t, 16);
            } else {
                aF = *(const bf16x8*)&aggb[(size_t)arow * 256 + (kk - 4) * 32 + quad * 8];
            }
#pragma unroll
            for (int nt = 0; nt < 4; ++nt) {
                const int n = w * 64 + nt * 16 + mloc;
                u16x8 t;
#pragma unroll
                for (int e = 0; e < 8; ++e)
                    t[e] = f2bf(Wo1[(kk * 32 + quad * 8 + e) * 256 + n]);
                bf16x8 bF;
                __builtin_memcpy(&bF, &t, 16);
                acc[nt] = __builtin_amdgcn_mfma_f32_16x16x32_bf16(aF, bF, acc[nt], 0, 0, 0);
            }
        }
#pragma unroll
        for (int nt = 0; nt < 4; ++nt) {
            const int n = w * 64 + nt * 16 + mloc;
            const float bias = bo1[n];
            if (quad < 2) {
#pragma unroll
                for (int r = 0; r < 4; ++r) {
                    float v = acc[nt][r] + bias;
                    p1S[(quad * 4 + r) * 264 + n] = f2bf(v > 0.f ? v : 0.f);
                }
            }
        }
    }
    LBAR();
    {   // ---- L2: K=256 (8 chunks), N=256 ----
        f32x4 acc[4];
#pragma unroll
        for (int nt = 0; nt < 4; ++nt) acc[nt] = (f32x4){0.f, 0.f, 0.f, 0.f};
        for (int kk = 0; kk < 8; ++kk) {
            bf16x8 aF = *(const bf16x8*)&p1S[(mloc & 7) * 264 + kk * 32 + quad * 8];
#pragma unroll
            for (int nt = 0; nt < 4; ++nt) {
                const int n = w * 64 + nt * 16 + mloc;
                u16x8 t;
#pragma unroll
                for (int e = 0; e < 8; ++e)
                    t[e] = f2bf(Wo2[(kk * 32 + quad * 8 + e) * 256 + n]);
                bf16x8 bF;
                __builtin_memcpy(&bF, &t, 16);
                acc[nt] = __builtin_amdgcn_mfma_f32_16x16x32_bf16(aF, bF, acc[nt], 0, 0, 0);
            }
        }
#pragma unroll
        for (int nt = 0; nt < 4; ++nt) {
            const int n = w * 64 + nt * 16 + mloc;
            const float bias = bo2[n];
            if (quad < 2) {
#pragma unroll
                for (int r = 0; r < 4; ++r) {
                    float v = acc[nt][r] + bias;
                    p2S[(quad * 4 + r) * 264 + n] = f2bf(v > 0.f ? v : 0.f);
                }
            }
        }
    }
    LBAR();
    {   // ---- L3: K=256 (8 chunks), N=128, residual ----
        f32x4 acc[2];
#pragma unroll
        for (int nt = 0; nt < 2; ++nt) acc[nt] = (f32x4){0.f, 0.f, 0.f, 0.f};
        for (int kk = 0; kk < 8; ++kk) {
            bf16x8 aF = *(const bf16x8*)&p2S[(mloc & 7) * 264 + kk * 32 + quad * 8];
#pragma unroll
            for (int nt = 0; nt < 2; ++nt) {
                const int n = w * 32 + nt * 16 + mloc;
                u16x8 t;
#pragma unroll
                for (int e = 0; e < 8; ++e)
                    t[e] = f2bf(Wo3[(kk * 32 + quad * 8 + e) * 128 + n]);
                bf16x8 bF;
                __builtin_memcpy(&bF, &t, 16);
                acc[nt] = __builtin_amdgcn_mfma_f32_16x16x32_bf16(aF, bF, acc[nt], 0, 0, 0);
            }
        }
#pragma unroll
        for (int nt = 0; nt < 2; ++nt) {
            const int n = w * 32 + nt * 16 + mloc;
            const float bias = bo3[n];
            if (quad < 2) {
#pragma unroll
                for (int r = 0; r < 4; ++r) {
                    const int grow = row0 + quad * 4 + r;
                    out[grow * 128 + n] = x[grow * 128 + n] + acc[nt][r] + bias;
                }
            }
        }
    }
}

extern "C" void kernel_launch(void* const* d_in, const int* in_sizes, int n_in,
                              void* d_out, int out_size, void* d_ws, size_t ws_size,
                              hipStream_t stream) {
    const float* x   = (const float*)d_in[0];
    const float* rel = (const float*)d_in[1];
    const float* W1  = (const float*)d_in[4];
    const float* b1  = (const float*)d_in[5];
    const float* W2  = (const float*)d_in[6];
    const float* b2  = (const float*)d_in[7];
    const float* Wo1 = (const float*)d_in[8];
    const float* bo1 = (const float*)d_in[9];
    const float* Wo2 = (const float*)d_in[10];
    const float* bo2 = (const float*)d_in[11];
    const float* Wo3 = (const float*)d_in[12];
    const float* bo3 = (const float*)d_in[13];
    float* out = (float*)d_out;

    char* ws = (char*)d_ws;
    u16* W2t  = (u16*)(ws + WS_W2T);
    u16* R    = (u16*)(ws + WS_R);
    u16* S2   = (u16*)(ws + WS_S);
    u16* aggb = (u16*)(ws + WS_AGG);

    prep_rs_kernel<<<1024, 256, 0, stream>>>(W2, x, W1, b1, W2t, R, S2);
    edge12_kernel<<<2048, 256, 0, stream>>>(R, S2, rel, W2t, b2, aggb);
    outmlp6_kernel<<<256, 256, 0, stream>>>(x, aggb, Wo1, bo1, Wo2, bo2, Wo3, bo3, out);
}

// Round 18
// 180.950 us; speedup vs baseline: 1.4239x; 1.0505x over previous
//
#include <hip/hip_runtime.h>

// GraphDecoder (NRI) — round 27: edge16 = edge12's per-kT staging with a 2x
// BIGGER tile (2 receivers/block, grid 1024, acc[4][2]=128 regs at (256,2)).
// Tile-space map: smaller tiles/phases lost twice (R13 117us, R25 101us);
// bigger-with-proven-structure is the untried quadrant. Halves per-unit-work
// fixed costs (8 barriers, sreg reload, Bb prefetch, epilogue) at 2 blocks/CU.
// Reg audit: acc 128 + Bb 32 + sreg 32 + misc ~25 = ~217 <= 256 cap (no
// R12-style spill possible). LDS 74KB -> 2 blocks/CU. prep (R26 merged) and
// outmlp6 byte-identical. B=32, N=64, F=128, K=4, H=M=NH=256, E=4032.

#define B_ 32
#define N_ 64
#define F_ 128
#define K_ 4
#define E_ 4032

// ws layout (bytes): total 9,961,472 <= proven 9,994,240
#define WS_W2T 0u
#define WS_R   524288u
#define WS_S   4718592u
#define WS_AGG 8912896u

typedef unsigned short u16;
typedef u16    u16x4  __attribute__((ext_vector_type(4)));
typedef u16    u16x8  __attribute__((ext_vector_type(8)));
typedef __bf16 bf16x8 __attribute__((ext_vector_type(8)));
typedef float  f32x4  __attribute__((ext_vector_type(4)));
typedef float  f32x16 __attribute__((ext_vector_type(16)));

__device__ __forceinline__ u16 f2bf(float f) {
    unsigned u; __builtin_memcpy(&u, &f, 4);
    return (u16)((u + 0x7FFFu + ((u >> 16) & 1u)) >> 16);
}
__device__ __forceinline__ float bf2f(u16 u) {
    unsigned v = ((unsigned)u) << 16;
    float f; __builtin_memcpy(&f, &v, 4); return f;
}

// raw barrier (LDS-only handoff; keeps vmem prefetch in flight)
#define LBAR() do { \
    asm volatile("s_waitcnt lgkmcnt(0)" ::: "memory"); \
    __builtin_amdgcn_s_barrier(); \
    __builtin_amdgcn_sched_barrier(0); \
} while (0)

// ---------------- fused prep: W2t conversion inlined + R/S2 tables (R26-proven) ----------------
// S2 kk-chunked: S2[((k*8+kc)*2048 + b*64 + row)*32 + kk_local]  (kc = kk>>5)
__global__ __launch_bounds__(256) void prep_rs_kernel(
    const float* __restrict__ W2, const float* __restrict__ x,
    const float* __restrict__ W1, const float* __restrict__ b1,
    u16* __restrict__ W2t, u16* __restrict__ R, u16* __restrict__ S)
{
    __shared__ u16 ldsA[64 * 136];
    __shared__ u16 ldsW[32 * 136];
    const int tid = threadIdx.x;

    {   // W2t: linear coalesced read, scattered 2B write (fire-and-forget)
        unsigned gid = blockIdx.x * 256u + tid;
        unsigned n = gid & 255u, kk = (gid >> 8) & 255u, k = gid >> 16;
        unsigned dst = (k * 8u + (kk >> 5)) * 8192u
                     + ((((kk >> 4) & 1u) * 2u) + ((kk >> 3) & 1u)) * 2048u
                     + n * 8u + (kk & 7u);
        W2t[dst] = f2bf(W2[gid]);
    }

    // R/S tables: (k, half, b) x ch4; ch covers 2 c-chunks.
    const int lane = tid & 63, w = tid >> 6;
    const int quad = lane >> 4, mloc = lane & 15;
    const int bx = blockIdx.x;
    const int ch = bx & 3;
    const int bq = bx >> 2;
    const int k = bq >> 6, half = (bq >> 5) & 1, b = bq & 31;

    for (int idx = tid; idx < 2048; idx += 256) {
        int row = idx >> 5, c4 = idx & 31;
        f32x4 v = *(const f32x4*)&x[(b * 64 + row) * 128 + c4 * 4];
        u16x4 o;
#pragma unroll
        for (int e = 0; e < 4; ++e) o[e] = f2bf(v[e]);
        *(u16x4*)&ldsA[row * 136 + c4 * 4] = o;
    }
    __syncthreads();

    bf16x8 aF[4];
#pragma unroll
    for (int ks = 0; ks < 4; ++ks)
        aF[ks] = *(const bf16x8*)&ldsA[(w * 16 + mloc) * 136 + quad * 8 + ks * 32];

    u16* dst = half ? S : R;
    for (int c = ch * 2; c < ch * 2 + 2; ++c) {
        __syncthreads();
        for (int idx = tid; idx < 4096; idx += 256) {
            int n = idx & 31, f = idx >> 5;
            ldsW[n * 136 + f] = f2bf(W1[(k * 256 + half * 128 + f) * 256 + c * 32 + n]);
        }
        __syncthreads();
#pragma unroll
        for (int nt = 0; nt < 2; ++nt) {
            f32x4 acc = (f32x4){0.f, 0.f, 0.f, 0.f};
            const int boff = (nt * 16 + mloc) * 136 + quad * 8;
#pragma unroll
            for (int ks = 0; ks < 4; ++ks)
                acc = __builtin_amdgcn_mfma_f32_16x16x32_bf16(
                    aF[ks], *(const bf16x8*)&ldsW[boff + ks * 32], acc, 0, 0, 0);
            const int n = c * 32 + nt * 16 + mloc;
            const float bias = half ? 0.f : b1[k * 256 + n];
#pragma unroll
            for (int r = 0; r < 4; ++r) {
                int row = w * 16 + quad * 4 + r;
                if (half) {
                    dst[((size_t)((k * 8 + c) * 2048 + b * 64 + row)) * 32 + nt * 16 + mloc]
                        = f2bf(acc[r] + bias);
                } else {
                    dst[((size_t)(k * 2048 + b * 64 + row)) * 256 + n] = f2bf(acc[r] + bias);
                }
            }
        }
    }
}

// ---------------- edge kernel: 2 receivers/block, per-kT staged H, (256,2) ----------------
__global__ __launch_bounds__(256, 2) void edge16_kernel(
    const u16* __restrict__ R, const u16* __restrict__ S2,
    const float* __restrict__ rel, const u16* __restrict__ W2t,
    const float* __restrict__ b2, u16* __restrict__ aggb)
{
    __shared__ u16   Hs[32][128][8];  // H tile for one kT: [g][recv*64+row][8kk] — 64KB
    __shared__ float Rf[2][4][256];   // both receivers' R rows, f32 — 8KB
    __shared__ float rtS[2][4][64];   // rel_type [recv][k][j], self=0 — 2KB

    const int tid  = threadIdx.x;
    const int lane = tid & 63;
    const int w    = tid >> 6;        // n-quarter (MFMA) AND kk32-subgroup (build)
    const int l31  = lane & 31;
    const int lh   = lane >> 5;
    // XCD swizzle for 1024 blocks (bijective: 1024 % 8 == 0)
    const int bid  = ((blockIdx.x & 7) << 7) | (blockIdx.x >> 3);
    const int b    = bid >> 5;
    const int i0   = (bid & 31) * 2;  // receiver pair

    // rtS: self-edge trick, 2 entries/thread
    for (int t = tid; t < 512; t += 256) {
        int recv = t >> 8, rem = t & 255, k = rem >> 6, j = rem & 63;
        int i = i0 + recv;
        float v = 0.f;
        if (j != i) v = rel[((size_t)(b * E_) + i * 63 + (j - (j > i))) * 4 + k];
        rtS[recv][k][j] = v;
    }
    // Rf: both receivers, 8 f32/thread
    {
        int recv = tid >> 7, k = (tid >> 5) & 3, e8 = tid & 31;
        u16x8 t8 = *(const u16x8*)&R[((size_t)(k * 2048 + b * 64 + i0 + recv)) * 256 + e8 * 8];
#pragma unroll
        for (int e = 0; e < 8; ++e) Rf[recv][k][e8 * 8 + e] = bf2f(t8[e]);
    }

    u16x8 sreg[8];
#pragma unroll
    for (int s = 0; s < 8; ++s)
        sreg[s] = *(const u16x8*)&S2[((size_t)(s * 2048 + b * 64 + lane)) * 32 + w * 8];

    __syncthreads();

    const u16* Wb = W2t + lh * 2048 + (w * 64 + l31) * 8;

    float amsg[2][2] = {{0.f, 0.f}, {0.f, 0.f}};

    for (int kT = 0; kT < 4; ++kT) {
        bf16x8 Bb[2][2][2];   // [kc parity][ks2][nt] — static indices
#pragma unroll
        for (int ks2 = 0; ks2 < 2; ++ks2) {
            const u16* wp = Wb + (size_t)(kT * 8) * 8192 + ks2 * 4096;
            Bb[0][ks2][0] = *(const bf16x8*)(wp);
            Bb[0][ks2][1] = *(const bf16x8*)(wp + 256);
        }
        // ---- build H(kT) for BOTH receivers: conflict-free contiguous writes ----
#pragma unroll
        for (int s = 0; s < 8; ++s) {
#pragma unroll
            for (int recv = 0; recv < 2; ++recv) {
                const float* rp = &Rf[recv][kT][s * 32 + w * 8];
                f32x4 r0 = *(const f32x4*)rp, r1 = *(const f32x4*)(rp + 4);
                bf16x8 o;
#pragma unroll
                for (int e = 0; e < 4; ++e) {
                    o[e]     = (__bf16)fmaxf(r0[e] + bf2f(sreg[s][e]),     0.f);
                    o[4 + e] = (__bf16)fmaxf(r1[e] + bf2f(sreg[s][4 + e]), 0.f);
                }
                *(bf16x8*)&Hs[s * 4 + w][recv * 64 + lane][0] = o;
            }
        }
        __syncthreads();   // H(kT) visible

        f32x16 acc[4][2];
#pragma unroll
        for (int mt = 0; mt < 4; ++mt)
#pragma unroll
            for (int nt = 0; nt < 2; ++nt) acc[mt][nt] = (f32x16)(0.f);

#pragma unroll
        for (int kc = 0; kc < 8; ++kc) {
            const int cur = kc & 1, nxt = cur ^ 1;
            // reload sreg for kT+1 (regs dead after the build consumed them)
            if (kc == 0 && kT < 3) {
#pragma unroll
                for (int s = 0; s < 8; ++s)
                    sreg[s] = *(const u16x8*)&S2[((size_t)(((kT + 1) * 8 + s) * 2048 + b * 64 + lane)) * 32 + w * 8];
            }
            // prefetch B(kc+1)
            if (kc < 7) {
#pragma unroll
                for (int ks2 = 0; ks2 < 2; ++ks2) {
                    const u16* wp = Wb + (size_t)(kT * 8 + kc + 1) * 8192 + ks2 * 4096;
                    Bb[nxt][ks2][0] = *(const bf16x8*)(wp);
                    Bb[nxt][ks2][1] = *(const bf16x8*)(wp + 256);
                }
            }
#pragma unroll
            for (int ks2 = 0; ks2 < 2; ++ks2) {
                const int g = kc * 4 + ks2 * 2 + lh;
                bf16x8 A0 = *(const bf16x8*)&Hs[g][l31][0];
                bf16x8 A1 = *(const bf16x8*)&Hs[g][32 + l31][0];
                bf16x8 A2 = *(const bf16x8*)&Hs[g][64 + l31][0];
                bf16x8 A3 = *(const bf16x8*)&Hs[g][96 + l31][0];
                acc[0][0] = __builtin_amdgcn_mfma_f32_32x32x16_bf16(A0, Bb[cur][ks2][0], acc[0][0], 0, 0, 0);
                acc[0][1] = __builtin_amdgcn_mfma_f32_32x32x16_bf16(A0, Bb[cur][ks2][1], acc[0][1], 0, 0, 0);
                acc[1][0] = __builtin_amdgcn_mfma_f32_32x32x16_bf16(A1, Bb[cur][ks2][0], acc[1][0], 0, 0, 0);
                acc[1][1] = __builtin_amdgcn_mfma_f32_32x32x16_bf16(A1, Bb[cur][ks2][1], acc[1][1], 0, 0, 0);
                acc[2][0] = __builtin_amdgcn_mfma_f32_32x32x16_bf16(A2, Bb[cur][ks2][0], acc[2][0], 0, 0, 0);
                acc[2][1] = __builtin_amdgcn_mfma_f32_32x32x16_bf16(A2, Bb[cur][ks2][1], acc[2][1], 0, 0, 0);
                acc[3][0] = __builtin_amdgcn_mfma_f32_32x32x16_bf16(A3, Bb[cur][ks2][0], acc[3][0], 0, 0, 0);
                acc[3][1] = __builtin_amdgcn_mfma_f32_32x32x16_bf16(A3, Bb[cur][ks2][1], acc[3][1], 0, 0, 0);
            }
        }

        // ---- per-kT epilogue: bias + relu + rel_type-weighted row fold ----
#pragma unroll
        for (int nt = 0; nt < 2; ++nt) {
            const float bias = b2[kT * 256 + w * 64 + nt * 32 + l31];
#pragma unroll
            for (int mt = 0; mt < 4; ++mt) {
                const int recv = mt >> 1;
                float s = 0.f;
#pragma unroll
                for (int rq = 0; rq < 4; ++rq) {
                    f32x4 rt4 = *(const f32x4*)&rtS[recv][kT][(mt & 1) * 32 + rq * 8 + 4 * lh];
#pragma unroll
                    for (int e = 0; e < 4; ++e) {
                        float v = acc[mt][nt][rq * 4 + e] + bias;
                        v = v > 0.f ? v : 0.f;
                        s += rt4[e] * v;
                    }
                }
                amsg[recv][nt] += s;
            }
        }
        __syncthreads();
    }

    // fold lh halves; unique writer per slot
#pragma unroll
    for (int recv = 0; recv < 2; ++recv)
#pragma unroll
        for (int nt = 0; nt < 2; ++nt) {
            float s = amsg[recv][nt] + __shfl_xor(amsg[recv][nt], 32);
            if (lh == 0)
                aggb[(size_t)(b * 64 + i0 + recv) * 256 + w * 64 + nt * 32 + l31] = f2bf(s);
        }
}

// ---------------- output MLP: 256 blocks x 8 rows, barrier-free layers (R23-proven) ----------------
__global__ __launch_bounds__(256) void outmlp6_kernel(
    const float* __restrict__ x, const u16* __restrict__ aggb,
    const float* __restrict__ Wo1, const float* __restrict__ bo1,
    const float* __restrict__ Wo2, const float* __restrict__ bo2,
    const float* __restrict__ Wo3, const float* __restrict__ bo3,
    float* __restrict__ out)
{
    __shared__ u16 p1S[8 * 264];
    __shared__ u16 p2S[8 * 264];
    const int tid = threadIdx.x, lane = tid & 63, w = tid >> 6;   // w = n-quarter
    const int quad = lane >> 4, mloc = lane & 15;
    const int row0 = blockIdx.x * 8;
    const int arow = row0 + (mloc & 7);    // duplicated A row

    {   // ---- L1: K=384 (12 chunks), N=256, aug=[x|agg] ----
        f32x4 acc[4];
#pragma unroll
        for (int nt = 0; nt < 4; ++nt) acc[nt] = (f32x4){0.f, 0.f, 0.f, 0.f};
        for (int kk = 0; kk < 12; ++kk) {
            bf16x8 aF;
            if (kk < 4) {
                u16x8 t;
#pragma unroll
                for (int e = 0; e < 8; ++e) t[e] = f2bf(x[arow * 128 + kk * 32 + quad * 8 + e]);
                __builtin_memcpy(&aF, &t, 16);
            } else {
                aF = *(const bf16x8*)&aggb[(size_t)arow * 256 + (kk - 4) * 32 + quad * 8];
            }
#pragma unroll
            for (int nt = 0; nt < 4; ++nt) {
                const int n = w * 64 + nt * 16 + mloc;
                u16x8 t;
#pragma unroll
                for (int e = 0; e < 8; ++e)
                    t[e] = f2bf(Wo1[(kk * 32 + quad * 8 + e) * 256 + n]);
                bf16x8 bF;
                __builtin_memcpy(&bF, &t, 16);
                acc[nt] = __builtin_amdgcn_mfma_f32_16x16x32_bf16(aF, bF, acc[nt], 0, 0, 0);
            }
        }
#pragma unroll
        for (int nt = 0; nt < 4; ++nt) {
            const int n = w * 64 + nt * 16 + mloc;
            const float bias = bo1[n];
            if (quad < 2) {
#pragma unroll
                for (int r = 0; r < 4; ++r) {
                    float v = acc[nt][r] + bias;
                    p1S[(quad * 4 + r) * 264 + n] = f2bf(v > 0.f ? v : 0.f);
                }
            }
        }
    }
    LBAR();
    {   // ---- L2: K=256 (8 chunks), N=256 ----
        f32x4 acc[4];
#pragma unroll
        for (int nt = 0; nt < 4; ++nt) acc[nt] = (f32x4){0.f, 0.f, 0.f, 0.f};
        for (int kk = 0; kk < 8; ++kk) {
            bf16x8 aF = *(const bf16x8*)&p1S[(mloc & 7) * 264 + kk * 32 + quad * 8];
#pragma unroll
            for (int nt = 0; nt < 4; ++nt) {
                const int n = w * 64 + nt * 16 + mloc;
                u16x8 t;
#pragma unroll
                for (int e = 0; e < 8; ++e)
                    t[e] = f2bf(Wo2[(kk * 32 + quad * 8 + e) * 256 + n]);
                bf16x8 bF;
                __builtin_memcpy(&bF, &t, 16);
                acc[nt] = __builtin_amdgcn_mfma_f32_16x16x32_bf16(aF, bF, acc[nt], 0, 0, 0);
            }
        }
#pragma unroll
        for (int nt = 0; nt < 4; ++nt) {
            const int n = w * 64 + nt * 16 + mloc;
            const float bias = bo2[n];
            if (quad < 2) {
#pragma unroll
                for (int r = 0; r < 4; ++r) {
                    float v = acc[nt][r] + bias;
                    p2S[(quad * 4 + r) * 264 + n] = f2bf(v > 0.f ? v : 0.f);
                }
            }
        }
    }
    LBAR();
    {   // ---- L3: K=256 (8 chunks), N=128, residual ----
        f32x4 acc[2];
#pragma unroll
        for (int nt = 0; nt < 2; ++nt) acc[nt] = (f32x4){0.f, 0.f, 0.f, 0.f};
        for (int kk = 0; kk < 8; ++kk) {
            bf16x8 aF = *(const bf16x8*)&p2S[(mloc & 7) * 264 + kk * 32 + quad * 8];
#pragma unroll
            for (int nt = 0; nt < 2; ++nt) {
                const int n = w * 32 + nt * 16 + mloc;
                u16x8 t;
#pragma unroll
                for (int e = 0; e < 8; ++e)
                    t[e] = f2bf(Wo3[(kk * 32 + quad * 8 + e) * 128 + n]);
                bf16x8 bF;
                __builtin_memcpy(&bF, &t, 16);
                acc[nt] = __builtin_amdgcn_mfma_f32_16x16x32_bf16(aF, bF, acc[nt], 0, 0, 0);
            }
        }
#pragma unroll
        for (int nt = 0; nt < 2; ++nt) {
            const int n = w * 32 + nt * 16 + mloc;
            const float bias = bo3[n];
            if (quad < 2) {
#pragma unroll
                for (int r = 0; r < 4; ++r) {
                    const int grow = row0 + quad * 4 + r;
                    out[grow * 128 + n] = x[grow * 128 + n] + acc[nt][r] + bias;
                }
            }
        }
    }
}

extern "C" void kernel_launch(void* const* d_in, const int* in_sizes, int n_in,
                              void* d_out, int out_size, void* d_ws, size_t ws_size,
                              hipStream_t stream) {
    const float* x   = (const float*)d_in[0];
    const float* rel = (const float*)d_in[1];
    const float* W1  = (const float*)d_in[4];
    const float* b1  = (const float*)d_in[5];
    const float* W2  = (const float*)d_in[6];
    const float* b2  = (const float*)d_in[7];
    const float* Wo1 = (const float*)d_in[8];
    const float* bo1 = (const float*)d_in[9];
    const float* Wo2 = (const float*)d_in[10];
    const float* bo2 = (const float*)d_in[11];
    const float* Wo3 = (const float*)d_in[12];
    const float* bo3 = (const float*)d_in[13];
    float* out = (float*)d_out;

    char* ws = (char*)d_ws;
    u16* W2t  = (u16*)(ws + WS_W2T);
    u16* R    = (u16*)(ws + WS_R);
    u16* S2   = (u16*)(ws + WS_S);
    u16* aggb = (u16*)(ws + WS_AGG);

    prep_rs_kernel<<<1024, 256, 0, stream>>>(W2, x, W1, b1, W2t, R, S2);
    edge16_kernel<<<1024, 256, 0, stream>>>(R, S2, rel, W2t, b2, aggb);
    outmlp6_kernel<<<256, 256, 0, stream>>>(x, aggb, Wo1, bo1, Wo2, bo2, Wo3, bo3, out);
}